// Round 11
// baseline (486.353 us; speedup 1.0000x reference)
//
#include <hip/hip_runtime.h>
#include <math.h>

#define BB 64
#define TT 128
#define HH 16
#define GG 64      // 4*H
#define IN0_ 65
#define VV 32000
#define NROWS (BB*TT)   // 8192
#define RSTRIDE 68      // insh row stride (floats), 16B-aligned, bank-skewed

typedef float f32x4 __attribute__((ext_vector_type(4)));

__device__ __forceinline__ float sigf(float x) {
    return 1.0f / (1.0f + __expf(-x));
}
__device__ __forceinline__ float tanhfast(float x) {
    return 1.0f - 2.0f / (__expf(2.0f * x) + 1.0f);
}

// ---------------- Kernel A: fused embed + xproj0 + 2-layer LSTM recurrence ----------
// 64 blocks (one per batch) x 256 threads.  (byte-identical to round 7)
__global__ __launch_bounds__(256) void fused_front(const float* __restrict__ x,
                           const float* __restrict__ emb,
                           const float* __restrict__ Wih0, const float* __restrict__ bih0,
                           const float* __restrict__ bhh0,
                           const float* __restrict__ h0in, const float* __restrict__ c0in,
                           const float* __restrict__ Whh0,
                           const float* __restrict__ Wih1, const float* __restrict__ Whh1,
                           const float* __restrict__ bih1, const float* __restrict__ bhh1,
                           float* __restrict__ y1, float* __restrict__ outTail) {
    __shared__ float insh[TT * RSTRIDE];   // 34816 B: inp rows, overwritten by xp rows
    __shared__ float wsh[GG * IN0_];       // 16640 B: Wih0 staged
    const int b   = blockIdx.x;
    const int tid = threadIdx.x;
    const int wave = tid >> 6, g = tid & 63;
    const float* xb = x + (size_t)b * TT * 9;

    // stage Wih0 (coalesced float4)
    for (int i = tid; i < GG * IN0_ / 4; i += 256) {
        float4 wv = *reinterpret_cast<const float4*>(Wih0 + i * 4);
        wsh[i*4+0] = wv.x; wsh[i*4+1] = wv.y; wsh[i*4+2] = wv.z; wsh[i*4+3] = wv.w;
    }
    // gather embeddings: 128 rows x 8 feats x 2 half-float4s = 2048 float4 loads
    #pragma unroll
    for (int it = 0; it < 8; ++it) {
        int q = tid + it * 256;          // 0..2047
        int p = q >> 1, half = q & 1;
        int r = p >> 3, f = p & 7;
        int idx = (int)xb[r * 9 + f];
        const float* er = emb + (size_t)idx * 8 + half * 4;
        float4 e = *reinterpret_cast<const float4*>(er);
        float* d = &insh[r * RSTRIDE + f * 8 + half * 4];
        d[0] = e.x; d[1] = e.y; d[2] = e.z; d[3] = e.w;
    }
    if (tid < TT) insh[tid * RSTRIDE + 64] = xb[tid * 9 + 8];
    __syncthreads();

    // phase 1 compute: wave handles rows [wave*32, wave*32+32)
    {
        float wreg[IN0_];
        #pragma unroll
        for (int k = 0; k < IN0_; ++k) wreg[k] = wsh[g * IN0_ + k];
        const float bias0 = bih0[g] + bhh0[g];
        for (int r = 0; r < 32; ++r) {
            const int row = wave * 32 + r;
            const float* ir = &insh[row * RSTRIDE];
            float a0 = bias0, a1 = 0.0f, a2 = 0.0f, a3 = 0.0f;
            #pragma unroll
            for (int k4 = 0; k4 < 16; ++k4) {
                f32x4 v = *reinterpret_cast<const f32x4*>(ir + k4 * 4);
                float p0 = v.x * wreg[k4*4+0] + v.y * wreg[k4*4+1]
                         + v.z * wreg[k4*4+2] + v.w * wreg[k4*4+3];
                if ((k4 & 3) == 0) a0 += p0;
                else if ((k4 & 3) == 1) a1 += p0;
                else if ((k4 & 3) == 2) a2 += p0;
                else a3 += p0;
            }
            float acc = (a0 + a1) + (a2 + a3) + ir[64] * wreg[64];
            insh[row * RSTRIDE + g] = acc;   // xp overwrites inp row (reads done)
        }
    }
    __syncthreads();

    if (tid >= 64) return;   // phase 2: wave 0 only

    const int j = g & 15;
    float w0[HH], wi1[HH], w1[HH];
    #pragma unroll
    for (int k = 0; k < HH; ++k) {
        w0[k]  = Whh0[g * HH + k];
        wi1[k] = Wih1[g * HH + k];
        w1[k]  = Whh1[g * HH + k];
    }
    const float bias1 = bih1[g] + bhh1[g];

    float h0v = h0in[b * HH + j];
    float h1v = h0in[BB * HH + b * HH + j];
    float c0v = c0in[b * HH + j];
    float c1v = c0in[BB * HH + b * HH + j];

    // prologue: layer0 step 0
    {
        float aa = insh[g], ab = 0.0f;
        #pragma unroll
        for (int k = 0; k < 8; ++k) {
            aa += __shfl(h0v, k) * w0[k];
            ab += __shfl(h0v, k + 8) * w0[k + 8];
        }
        float acc = aa + ab;
        float iv = __shfl(acc, j), fv = __shfl(acc, j + 16);
        float gv = __shfl(acc, j + 32), ov = __shfl(acc, j + 48);
        c0v = sigf(fv) * c0v + sigf(iv) * tanhfast(gv);
        h0v = sigf(ov) * tanhfast(c0v);
    }

    for (int t = 0; t < TT - 1; ++t) {
        float xpn = insh[(t + 1) * RSTRIDE + g];
        float a1a = bias1, a1b = 0.0f, a1c = 0.0f, a1d = 0.0f;
        float a0a = 0.0f,  a0b = 0.0f;
        #pragma unroll
        for (int k = 0; k < 8; ++k) {
            float h0k  = __shfl(h0v, k);
            float h0k8 = __shfl(h0v, k + 8);
            float h1k  = __shfl(h1v, k);
            float h1k8 = __shfl(h1v, k + 8);
            a1a += h0k  * wi1[k];
            a1b += h0k8 * wi1[k + 8];
            a1c += h1k  * w1[k];
            a1d += h1k8 * w1[k + 8];
            a0a += h0k  * w0[k];
            a0b += h0k8 * w0[k + 8];
        }
        float acc1 = (a1a + a1b) + (a1c + a1d);
        float acc0 = xpn + a0a + a0b;
        float iv1 = __shfl(acc1, j), fv1 = __shfl(acc1, j + 16);
        float gv1 = __shfl(acc1, j + 32), ov1 = __shfl(acc1, j + 48);
        float iv0 = __shfl(acc0, j), fv0 = __shfl(acc0, j + 16);
        float gv0 = __shfl(acc0, j + 32), ov0 = __shfl(acc0, j + 48);
        c1v = sigf(fv1) * c1v + sigf(iv1) * tanhfast(gv1);
        h1v = sigf(ov1) * tanhfast(c1v);
        c0v = sigf(fv0) * c0v + sigf(iv0) * tanhfast(gv0);
        h0v = sigf(ov0) * tanhfast(c0v);
        if (g < HH) y1[(size_t)(b * TT + t) * HH + g] = h1v;
    }

    // epilogue: layer1 step TT-1
    {
        float a1a = bias1, a1b = 0.0f, a1c = 0.0f, a1d = 0.0f;
        #pragma unroll
        for (int k = 0; k < 8; ++k) {
            float h0k  = __shfl(h0v, k);
            float h0k8 = __shfl(h0v, k + 8);
            float h1k  = __shfl(h1v, k);
            float h1k8 = __shfl(h1v, k + 8);
            a1a += h0k  * wi1[k];
            a1b += h0k8 * wi1[k + 8];
            a1c += h1k  * w1[k];
            a1d += h1k8 * w1[k + 8];
        }
        float acc1 = (a1a + a1b) + (a1c + a1d);
        float iv1 = __shfl(acc1, j), fv1 = __shfl(acc1, j + 16);
        float gv1 = __shfl(acc1, j + 32), ov1 = __shfl(acc1, j + 48);
        c1v = sigf(fv1) * c1v + sigf(iv1) * tanhfast(gv1);
        h1v = sigf(ov1) * tanhfast(c1v);
        if (g < HH) y1[(size_t)(b * TT + TT - 1) * HH + g] = h1v;
    }

    if (g < HH) {
        outTail[b * HH + g]               = h0v;
        outTail[BB * HH + b * HH + g]     = h1v;
        outTail[2 * BB * HH + b * HH + g] = c0v;
        outTail[3 * BB * HH + b * HH + g] = c1v;
    }
}

// ---------------- Kernel B: FC head — byte-identical to round 7 --------------------
__global__ __launch_bounds__(256) void fc_kernel(const float* __restrict__ y1,
                          const float* __restrict__ fcw, const float* __restrict__ fcb,
                          float* __restrict__ out) {
    const int tid  = threadIdx.x;
    const int v0   = blockIdx.x * 1024 + tid * 4;   // column slice (fast grid dim)
    const int row0 = blockIdx.y * 32;               // row band

    if (v0 >= VV) return;

    float w[4][HH];
    #pragma unroll
    for (int jj = 0; jj < 4; ++jj) {
        const float4* wp = reinterpret_cast<const float4*>(fcw + (size_t)(v0 + jj) * HH);
        float4 a = wp[0], b = wp[1], c = wp[2], d = wp[3];
        w[jj][0]=a.x; w[jj][1]=a.y; w[jj][2]=a.z; w[jj][3]=a.w;
        w[jj][4]=b.x; w[jj][5]=b.y; w[jj][6]=b.z; w[jj][7]=b.w;
        w[jj][8]=c.x; w[jj][9]=c.y; w[jj][10]=c.z; w[jj][11]=c.w;
        w[jj][12]=d.x; w[jj][13]=d.y; w[jj][14]=d.z; w[jj][15]=d.w;
    }
    const float4 bias = *reinterpret_cast<const float4*>(fcb + v0);

    // y rows are wave-uniform (address independent of tid): broadcast loads
    const f32x4* yrow = reinterpret_cast<const f32x4*>(y1 + (size_t)row0 * HH);

    float* orow = out + (size_t)row0 * VV + v0;
    #pragma unroll 4
    for (int r = 0; r < 32; ++r) {
        f32x4 y0 = yrow[r * 4 + 0];
        f32x4 y1v = yrow[r * 4 + 1];
        f32x4 y2 = yrow[r * 4 + 2];
        f32x4 y3 = yrow[r * 4 + 3];
        float a0 = bias.x, a1 = bias.y, a2 = bias.z, a3 = bias.w;
        #pragma unroll
        for (int jj = 0; jj < 4; ++jj) {
            float* wj = w[jj];
            float acc = y0.x*wj[0] + y0.y*wj[1] + y0.z*wj[2] + y0.w*wj[3]
                      + y1v.x*wj[4] + y1v.y*wj[5] + y1v.z*wj[6] + y1v.w*wj[7]
                      + y2.x*wj[8] + y2.y*wj[9] + y2.z*wj[10] + y2.w*wj[11]
                      + y3.x*wj[12] + y3.y*wj[13] + y3.z*wj[14] + y3.w*wj[15];
            if (jj == 0) a0 += acc;
            else if (jj == 1) a1 += acc;
            else if (jj == 2) a2 += acc;
            else a3 += acc;
        }
        f32x4 o;
        o.x = a0; o.y = a1; o.z = a2; o.w = a3;
        __builtin_nontemporal_store(o, reinterpret_cast<f32x4*>(orow));
        orow += VV;
    }
}

extern "C" void kernel_launch(void* const* d_in, const int* in_sizes, int n_in,
                              void* d_out, int out_size, void* d_ws, size_t ws_size,
                              hipStream_t stream) {
    const float* x    = (const float*)d_in[0];
    const float* h0   = (const float*)d_in[1];
    const float* c0   = (const float*)d_in[2];
    const float* emb  = (const float*)d_in[3];
    const float* Wih0 = (const float*)d_in[4];
    const float* Whh0 = (const float*)d_in[5];
    const float* bih0 = (const float*)d_in[6];
    const float* bhh0 = (const float*)d_in[7];
    const float* Wih1 = (const float*)d_in[8];
    const float* Whh1 = (const float*)d_in[9];
    const float* bih1 = (const float*)d_in[10];
    const float* bhh1 = (const float*)d_in[11];
    const float* fcw  = (const float*)d_in[12];
    const float* fcb  = (const float*)d_in[13];

    float* out = (float*)d_out;
    float* y1  = (float*)d_ws;                     // NROWS*16 floats
    float* outTail = out + (size_t)NROWS * VV;     // hN then cN

    fused_front<<<BB, 256, 0, stream>>>(x, emb, Wih0, bih0, bhh0, h0, c0,
                                        Whh0, Wih1, Whh1, bih1, bhh1, y1, outTail);
    // MEASUREMENT ROUND: fc_kernel is idempotent; launching it twice is
    // correctness-preserving and dur(R11) - dur(R7) = steady-state FC time.
    fc_kernel<<<dim3(32, NROWS / 32), 256, 0, stream>>>(y1, fcw, fcb, out);
    fc_kernel<<<dim3(32, NROWS / 32), 256, 0, stream>>>(y1, fcw, fcb, out);
}

// Round 12
// 282.499 us; speedup vs baseline: 1.7216x; 1.7216x over previous
//
#include <hip/hip_runtime.h>
#include <math.h>

#define BB 64
#define TT 128
#define HH 16
#define GG 64      // 4*H
#define IN0_ 65
#define VV 32000
#define NROWS (BB*TT)   // 8192
#define RSTRIDE 68      // insh row stride (floats), 16B-aligned, bank-skewed

typedef float f32x4 __attribute__((ext_vector_type(4)));

__device__ __forceinline__ float sigf(float x) {
    return 1.0f / (1.0f + __expf(-x));
}
__device__ __forceinline__ float tanhfast(float x) {
    return 1.0f - 2.0f / (__expf(2.0f * x) + 1.0f);
}
// Broadcast lane k's value to all lanes via v_readlane (VALU/SGPR path, ~3 cyc)
// instead of __shfl's ds_bpermute (LDS unit, ~30-40 cyc; unhideable at 1 wave/SIMD).
__device__ __forceinline__ float bcast(float v, int lane) {
    return __uint_as_float(__builtin_amdgcn_readlane(__float_as_uint(v), lane));
}

// ---------------- Kernel A: fused embed + xproj0 + 2-layer LSTM recurrence ----------
// 64 blocks (one per batch) x 256 threads. Phase 1 identical to R7; phase 2's
// h-broadcasts switched from __shfl (bpermute) to readlane.
__global__ __launch_bounds__(256) void fused_front(const float* __restrict__ x,
                           const float* __restrict__ emb,
                           const float* __restrict__ Wih0, const float* __restrict__ bih0,
                           const float* __restrict__ bhh0,
                           const float* __restrict__ h0in, const float* __restrict__ c0in,
                           const float* __restrict__ Whh0,
                           const float* __restrict__ Wih1, const float* __restrict__ Whh1,
                           const float* __restrict__ bih1, const float* __restrict__ bhh1,
                           float* __restrict__ y1, float* __restrict__ outTail) {
    __shared__ float insh[TT * RSTRIDE];   // 34816 B: inp rows, overwritten by xp rows
    __shared__ float wsh[GG * IN0_];       // 16640 B: Wih0 staged
    const int b   = blockIdx.x;
    const int tid = threadIdx.x;
    const int wave = tid >> 6, g = tid & 63;
    const float* xb = x + (size_t)b * TT * 9;

    // stage Wih0 (coalesced float4)
    for (int i = tid; i < GG * IN0_ / 4; i += 256) {
        float4 wv = *reinterpret_cast<const float4*>(Wih0 + i * 4);
        wsh[i*4+0] = wv.x; wsh[i*4+1] = wv.y; wsh[i*4+2] = wv.z; wsh[i*4+3] = wv.w;
    }
    // gather embeddings: 128 rows x 8 feats x 2 half-float4s = 2048 float4 loads
    #pragma unroll
    for (int it = 0; it < 8; ++it) {
        int q = tid + it * 256;          // 0..2047
        int p = q >> 1, half = q & 1;
        int r = p >> 3, f = p & 7;
        int idx = (int)xb[r * 9 + f];
        const float* er = emb + (size_t)idx * 8 + half * 4;
        float4 e = *reinterpret_cast<const float4*>(er);
        float* d = &insh[r * RSTRIDE + f * 8 + half * 4];
        d[0] = e.x; d[1] = e.y; d[2] = e.z; d[3] = e.w;
    }
    if (tid < TT) insh[tid * RSTRIDE + 64] = xb[tid * 9 + 8];
    __syncthreads();

    // phase 1 compute: wave handles rows [wave*32, wave*32+32)
    {
        float wreg[IN0_];
        #pragma unroll
        for (int k = 0; k < IN0_; ++k) wreg[k] = wsh[g * IN0_ + k];
        const float bias0 = bih0[g] + bhh0[g];
        for (int r = 0; r < 32; ++r) {
            const int row = wave * 32 + r;
            const float* ir = &insh[row * RSTRIDE];
            float a0 = bias0, a1 = 0.0f, a2 = 0.0f, a3 = 0.0f;
            #pragma unroll
            for (int k4 = 0; k4 < 16; ++k4) {
                f32x4 v = *reinterpret_cast<const f32x4*>(ir + k4 * 4);
                float p0 = v.x * wreg[k4*4+0] + v.y * wreg[k4*4+1]
                         + v.z * wreg[k4*4+2] + v.w * wreg[k4*4+3];
                if ((k4 & 3) == 0) a0 += p0;
                else if ((k4 & 3) == 1) a1 += p0;
                else if ((k4 & 3) == 2) a2 += p0;
                else a3 += p0;
            }
            float acc = (a0 + a1) + (a2 + a3) + ir[64] * wreg[64];
            insh[row * RSTRIDE + g] = acc;   // xp overwrites inp row (reads done)
        }
    }
    __syncthreads();

    if (tid >= 64) return;   // phase 2: wave 0 only

    const int j = g & 15;
    float w0[HH], wi1[HH], w1[HH];
    #pragma unroll
    for (int k = 0; k < HH; ++k) {
        w0[k]  = Whh0[g * HH + k];
        wi1[k] = Wih1[g * HH + k];
        w1[k]  = Whh1[g * HH + k];
    }
    const float bias1 = bih1[g] + bhh1[g];

    float h0v = h0in[b * HH + j];
    float h1v = h0in[BB * HH + b * HH + j];
    float c0v = c0in[b * HH + j];
    float c1v = c0in[BB * HH + b * HH + j];

    // prologue: layer0 step 0
    {
        float aa = insh[g], ab = 0.0f;
        #pragma unroll
        for (int k = 0; k < 8; ++k) {
            aa += bcast(h0v, k) * w0[k];
            ab += bcast(h0v, k + 8) * w0[k + 8];
        }
        float acc = aa + ab;
        float iv = __shfl(acc, j), fv = __shfl(acc, j + 16);
        float gv = __shfl(acc, j + 32), ov = __shfl(acc, j + 48);
        c0v = sigf(fv) * c0v + sigf(iv) * tanhfast(gv);
        h0v = sigf(ov) * tanhfast(c0v);
    }

    for (int t = 0; t < TT - 1; ++t) {
        float xpn = insh[(t + 1) * RSTRIDE + g];
        float a1a = bias1, a1b = 0.0f, a1c = 0.0f, a1d = 0.0f;
        float a0a = 0.0f,  a0b = 0.0f;
        #pragma unroll
        for (int k = 0; k < 8; ++k) {
            float h0k  = bcast(h0v, k);
            float h0k8 = bcast(h0v, k + 8);
            float h1k  = bcast(h1v, k);
            float h1k8 = bcast(h1v, k + 8);
            a1a += h0k  * wi1[k];
            a1b += h0k8 * wi1[k + 8];
            a1c += h1k  * w1[k];
            a1d += h1k8 * w1[k + 8];
            a0a += h0k  * w0[k];
            a0b += h0k8 * w0[k + 8];
        }
        float acc1 = (a1a + a1b) + (a1c + a1d);
        float acc0 = xpn + a0a + a0b;
        float iv1 = __shfl(acc1, j), fv1 = __shfl(acc1, j + 16);
        float gv1 = __shfl(acc1, j + 32), ov1 = __shfl(acc1, j + 48);
        float iv0 = __shfl(acc0, j), fv0 = __shfl(acc0, j + 16);
        float gv0 = __shfl(acc0, j + 32), ov0 = __shfl(acc0, j + 48);
        c1v = sigf(fv1) * c1v + sigf(iv1) * tanhfast(gv1);
        h1v = sigf(ov1) * tanhfast(c1v);
        c0v = sigf(fv0) * c0v + sigf(iv0) * tanhfast(gv0);
        h0v = sigf(ov0) * tanhfast(c0v);
        if (g < HH) y1[(size_t)(b * TT + t) * HH + g] = h1v;
    }

    // epilogue: layer1 step TT-1
    {
        float a1a = bias1, a1b = 0.0f, a1c = 0.0f, a1d = 0.0f;
        #pragma unroll
        for (int k = 0; k < 8; ++k) {
            float h0k  = bcast(h0v, k);
            float h0k8 = bcast(h0v, k + 8);
            float h1k  = bcast(h1v, k);
            float h1k8 = bcast(h1v, k + 8);
            a1a += h0k  * wi1[k];
            a1b += h0k8 * wi1[k + 8];
            a1c += h1k  * w1[k];
            a1d += h1k8 * w1[k + 8];
        }
        float acc1 = (a1a + a1b) + (a1c + a1d);
        float iv1 = __shfl(acc1, j), fv1 = __shfl(acc1, j + 16);
        float gv1 = __shfl(acc1, j + 32), ov1 = __shfl(acc1, j + 48);
        c1v = sigf(fv1) * c1v + sigf(iv1) * tanhfast(gv1);
        h1v = sigf(ov1) * tanhfast(c1v);
        if (g < HH) y1[(size_t)(b * TT + TT - 1) * HH + g] = h1v;
    }

    if (g < HH) {
        outTail[b * HH + g]               = h0v;
        outTail[BB * HH + b * HH + g]     = h1v;
        outTail[2 * BB * HH + b * HH + g] = c0v;
        outTail[3 * BB * HH + b * HH + g] = c1v;
    }
}

// ---------------- Kernel B: FC head — byte-identical to round 7 --------------------
__global__ __launch_bounds__(256) void fc_kernel(const float* __restrict__ y1,
                          const float* __restrict__ fcw, const float* __restrict__ fcb,
                          float* __restrict__ out) {
    const int tid  = threadIdx.x;
    const int v0   = blockIdx.x * 1024 + tid * 4;   // column slice (fast grid dim)
    const int row0 = blockIdx.y * 32;               // row band

    if (v0 >= VV) return;

    float w[4][HH];
    #pragma unroll
    for (int jj = 0; jj < 4; ++jj) {
        const float4* wp = reinterpret_cast<const float4*>(fcw + (size_t)(v0 + jj) * HH);
        float4 a = wp[0], b = wp[1], c = wp[2], d = wp[3];
        w[jj][0]=a.x; w[jj][1]=a.y; w[jj][2]=a.z; w[jj][3]=a.w;
        w[jj][4]=b.x; w[jj][5]=b.y; w[jj][6]=b.z; w[jj][7]=b.w;
        w[jj][8]=c.x; w[jj][9]=c.y; w[jj][10]=c.z; w[jj][11]=c.w;
        w[jj][12]=d.x; w[jj][13]=d.y; w[jj][14]=d.z; w[jj][15]=d.w;
    }
    const float4 bias = *reinterpret_cast<const float4*>(fcb + v0);

    // y rows are wave-uniform (address independent of tid): broadcast loads
    const f32x4* yrow = reinterpret_cast<const f32x4*>(y1 + (size_t)row0 * HH);

    float* orow = out + (size_t)row0 * VV + v0;
    #pragma unroll 4
    for (int r = 0; r < 32; ++r) {
        f32x4 y0 = yrow[r * 4 + 0];
        f32x4 y1v = yrow[r * 4 + 1];
        f32x4 y2 = yrow[r * 4 + 2];
        f32x4 y3 = yrow[r * 4 + 3];
        float a0 = bias.x, a1 = bias.y, a2 = bias.z, a3 = bias.w;
        #pragma unroll
        for (int jj = 0; jj < 4; ++jj) {
            float* wj = w[jj];
            float acc = y0.x*wj[0] + y0.y*wj[1] + y0.z*wj[2] + y0.w*wj[3]
                      + y1v.x*wj[4] + y1v.y*wj[5] + y1v.z*wj[6] + y1v.w*wj[7]
                      + y2.x*wj[8] + y2.y*wj[9] + y2.z*wj[10] + y2.w*wj[11]
                      + y3.x*wj[12] + y3.y*wj[13] + y3.z*wj[14] + y3.w*wj[15];
            if (jj == 0) a0 += acc;
            else if (jj == 1) a1 += acc;
            else if (jj == 2) a2 += acc;
            else a3 += acc;
        }
        f32x4 o;
        o.x = a0; o.y = a1; o.z = a2; o.w = a3;
        __builtin_nontemporal_store(o, reinterpret_cast<f32x4*>(orow));
        orow += VV;
    }
}

extern "C" void kernel_launch(void* const* d_in, const int* in_sizes, int n_in,
                              void* d_out, int out_size, void* d_ws, size_t ws_size,
                              hipStream_t stream) {
    const float* x    = (const float*)d_in[0];
    const float* h0   = (const float*)d_in[1];
    const float* c0   = (const float*)d_in[2];
    const float* emb  = (const float*)d_in[3];
    const float* Wih0 = (const float*)d_in[4];
    const float* Whh0 = (const float*)d_in[5];
    const float* bih0 = (const float*)d_in[6];
    const float* bhh0 = (const float*)d_in[7];
    const float* Wih1 = (const float*)d_in[8];
    const float* Whh1 = (const float*)d_in[9];
    const float* bih1 = (const float*)d_in[10];
    const float* bhh1 = (const float*)d_in[11];
    const float* fcw  = (const float*)d_in[12];
    const float* fcb  = (const float*)d_in[13];

    float* out = (float*)d_out;
    float* y1  = (float*)d_ws;                     // NROWS*16 floats
    float* outTail = out + (size_t)NROWS * VV;     // hN then cN

    fused_front<<<BB, 256, 0, stream>>>(x, emb, Wih0, bih0, bhh0, h0, c0,
                                        Whh0, Wih1, Whh1, bih1, bhh1, y1, outTail);
    fc_kernel<<<dim3(32, NROWS / 32), 256, 0, stream>>>(y1, fcw, fcb, out);
}